// Round 6
// baseline (214.073 us; speedup 1.0000x reference)
//
#include <hip/hip_runtime.h>
#include <math.h>

// Problem constants (match reference setup_inputs)
#define Bn 4096
#define Sn 2048
#define BLOCK 256
#define CHUNK (Sn / BLOCK)       // 8 steps per thread
#define GRID 1024                // persistent blocks; 4 sequences per block
#define ITERS (Bn / GRID)
#define NM (Bn * BLOCK)          // total chunk matrices = 1,048,576

// All of one sequence's per-thread inputs, held in registers (13 loads).
struct SeqRegs {
    float4 e0, e1, e2, e3;                       // 16 VGPR
    int4 ta, tb, wa, wb, ia, ib, da, db;         // 32 VGPR
    int ptag;                                    // lane0-of-wave prev tag
};

__device__ __forceinline__ SeqRegs load_seq(
    const float* __restrict__ em, const int* __restrict__ tg,
    const int* __restrict__ wh, const int* __restrict__ it,
    const int* __restrict__ ds, int b, int t)
{
    SeqRegs r;
    const long base = (long)b * Sn;
    const float4* ep = (const float4*)(em + base * 2) + t * 4;
    const int4* tp = (const int4*)(tg + base) + t * 2;
    const int4* wp = (const int4*)(wh + base) + t * 2;
    const int4* ip = (const int4*)(it + base) + t * 2;
    const int4* dp = (const int4*)(ds + base) + t * 2;
    r.e0 = ep[0]; r.e1 = ep[1]; r.e2 = ep[2]; r.e3 = ep[3];
    r.ta = tp[0]; r.tb = tp[1];
    r.wa = wp[0]; r.wb = wp[1];
    r.ia = ip[0]; r.ib = ip[1];
    r.da = dp[0]; r.db = dp[1];
    // cross-wave prev_tag: only lane 0 of waves 1..3 needs a global read
    r.ptag = 0;
    if ((t & 63) == 0 && t > 0) r.ptag = tg[base + t * CHUNK - 1];
    return r;
}

// =====================================================================
// Kernel 1: persistent software-pipelined streamer.
// R5 post-mortem: every one-shot-block variant plateaued at ~75 us with
// only ~4 KB/CU of loads in flight (loads outstanding a small fraction
// of wave lifetime). This version keeps the NEXT sequence's 13 vector
// loads in flight during the CURRENT sequence's compute, pinned with
// sched_barrier(0) so the compiler can't re-batch them (R3 failure).
// =====================================================================
__global__ __launch_bounds__(BLOCK, 3) void crf_chunk(
    const float* __restrict__ emissions,     // [B, S, 2]
    const float* __restrict__ trans_params,  // [4, 2, 2]
    const int*   __restrict__ tags,          // [B, S]
    const int*   __restrict__ who2who,       // [B, S]
    const int*   __restrict__ intime,        // [B, S]
    const int*   __restrict__ distance,      // [B, S]
    float2*      __restrict__ wsA,           // [NM] (m00,m01)
    float2*      __restrict__ wsB,           // [NM] (m10,m11)
    float2*      __restrict__ wsC)           // [NM] (L, gold)
{
    const int t = threadIdx.x;

    // sel banks: [sel][i][j] at [sel*4 + i*2 + j]; sel==0 is zero/ones
    __shared__ __align__(16) float lbank[20];  // log-domain (gold path)
    __shared__ __align__(16) float ebank[20];  // exp(trans)  (forward scan)
    if (t < 20) {
        float v = (t < 4) ? 0.0f : trans_params[t - 4];
        lbank[t] = v;
        ebank[t] = __expf(v);    // sel 0 -> all-ones matrix
    }
    __syncthreads();             // only barrier in the kernel

    // process one sequence held in registers (validated math, R2-R5)
    auto process = [&](const SeqRegs& r, int b) {
        int tagv[CHUNK] = {r.ta.x, r.ta.y, r.ta.z, r.ta.w,
                           r.tb.x, r.tb.y, r.tb.z, r.tb.w};
        int wv[CHUNK]   = {r.wa.x, r.wa.y, r.wa.z, r.wa.w,
                           r.wb.x, r.wb.y, r.wb.z, r.wb.w};
        int iv[CHUNK]   = {r.ia.x, r.ia.y, r.ia.z, r.ia.w,
                           r.ib.x, r.ib.y, r.ib.z, r.ib.w};
        int dv[CHUNK]   = {r.da.x, r.da.y, r.da.z, r.da.w,
                           r.db.x, r.db.y, r.db.z, r.db.w};
        float emv[CHUNK][2] = {
            {r.e0.x, r.e0.y}, {r.e0.z, r.e0.w}, {r.e1.x, r.e1.y},
            {r.e1.z, r.e1.w}, {r.e2.x, r.e2.y}, {r.e2.z, r.e2.w},
            {r.e3.x, r.e3.y}, {r.e3.z, r.e3.w}};

        // prev_tag: last tag of thread t-1 via shuffle; wave boundary from
        // the masked global load staged with the batch
        int pt0 = __shfl_up(tagv[CHUNK - 1], 1);
        if ((t & 63) == 0) pt0 = r.ptag;       // t==0: unused (guard below)

        int sel[CHUNK];
        #pragma unroll
        for (int k = 0; k < CHUNK; ++k) {
            int w = wv[k], it2 = iv[k], d = dv[k];
            sel[k] = (w == -1) ? 0 : (w == 1) ? 1
                   : (it2 == 0) ? 2 : (d == 0) ? 3 : 4;
        }

        // linear-domain chunk scan (worst-case growth < 3e25, fp32 safe)
        float4 P0 = *(const float4*)(ebank + sel[0] * 4);
        float x00 = __expf(emv[0][0]), x01 = __expf(emv[0][1]);
        float m00 = P0.x * x00, m01 = P0.y * x01;
        float m10 = P0.z * x00, m11 = P0.w * x01;
        #pragma unroll
        for (int k = 1; k < CHUNK; ++k) {
            float4 P = *(const float4*)(ebank + sel[k] * 4);
            float x0 = __expf(emv[k][0]), x1 = __expf(emv[k][1]);
            float n00 = fmaf(m00, P.x, m01 * P.z) * x0;
            float n01 = fmaf(m00, P.y, m01 * P.w) * x1;
            float n10 = fmaf(m10, P.x, m11 * P.z) * x0;
            float n11 = fmaf(m10, P.y, m11 * P.w) * x1;
            m00 = n00; m01 = n01; m10 = n10; m11 = n11;
        }

        // gold path (log domain)
        float gold = 0.0f;
        #pragma unroll
        for (int k = 0; k < CHUNK; ++k) {
            int tg = tagv[k];
            gold += tg ? emv[k][1] : emv[k][0];
            if (k > 0 || t > 0) {            // no transition at global s==0
                int pt = (k == 0) ? pt0 : tagv[k - 1];
                gold += lbank[(sel[k] << 2) + (pt << 1) + tg];
            }
        }

        float mx  = fmaxf(fmaxf(m00, m01), fmaxf(m10, m11));
        float inv = 1.0f / mx;
        float L   = __logf(mx);
        const int gid = b * BLOCK + t;
        wsA[gid] = make_float2(m00 * inv, m01 * inv);
        wsB[gid] = make_float2(m10 * inv, m11 * inv);
        wsC[gid] = make_float2(L, gold);
    };

    // ---- software pipeline: prefetch seq i+1 while computing seq i ----
    int b = blockIdx.x;
    SeqRegs cur = load_seq(emissions, tags, who2who, intime, distance, b, t);
    #pragma unroll
    for (int itr = 0; itr < ITERS; ++itr) {
        SeqRegs nxt;
        if (itr + 1 < ITERS)
            nxt = load_seq(emissions, tags, who2who, intime, distance,
                           b + GRID, t);
        __builtin_amdgcn_sched_barrier(0);   // prefetch issued BEFORE compute
        process(cur, b);
        __builtin_amdgcn_sched_barrier(0);   // compute done before buffer swap
        cur = nxt;
        b += GRID;
    }
}

// =====================================================================
// Kernel 2: reduction. One wave per batch element (4 waves/block).
// =====================================================================
__global__ __launch_bounds__(BLOCK) void crf_reduce(
    const float2* __restrict__ wsA,
    const float2* __restrict__ wsB,
    const float2* __restrict__ wsC,
    float*        __restrict__ out)          // [2, B]
{
    const int lane = threadIdx.x & 63;
    const int wave = threadIdx.x >> 6;
    const int b = blockIdx.x * 4 + wave;

    const int idx4 = b * (BLOCK / 2) + lane * 2;     // float4 index into pairs
    const float4* A4 = (const float4*)wsA;
    const float4* B4 = (const float4*)wsB;
    const float4* C4 = (const float4*)wsC;
    float4 a0 = A4[idx4], a1 = A4[idx4 + 1];
    float4 b0 = B4[idx4], b1 = B4[idx4 + 1];
    float4 c0 = C4[idx4], c1 = C4[idx4 + 1];

    float m00 = a0.x, m01 = a0.y, m10 = b0.x, m11 = b0.y;
    float L = c0.x, gold = c0.y;
    {
        float q00[3] = {a0.z, a1.x, a1.z};
        float q01[3] = {a0.w, a1.y, a1.w};
        float q10[3] = {b0.z, b1.x, b1.z};
        float q11[3] = {b0.w, b1.y, b1.w};
        float qL[3]  = {c0.z, c1.x, c1.z};
        float qg[3]  = {c0.w, c1.y, c1.w};
        #pragma unroll
        for (int q = 0; q < 3; ++q) {
            float n00 = fmaf(m00, q00[q], m01 * q10[q]);
            float n01 = fmaf(m00, q01[q], m01 * q11[q]);
            float n10 = fmaf(m10, q00[q], m11 * q10[q]);
            float n11 = fmaf(m10, q01[q], m11 * q11[q]);
            m00 = n00; m01 = n01; m10 = n10; m11 = n11;
            L += qL[q]; gold += qg[q];
        }
        float mx  = fmaxf(fmaxf(m00, m01), fmaxf(m10, m11));
        float inv = 1.0f / mx;
        L += __logf(mx);
        m00 *= inv; m01 *= inv; m10 *= inv; m11 *= inv;
    }

    #pragma unroll
    for (int m = 1; m < 64; m <<= 1) {
        float o00 = __shfl_xor(m00, m);
        float o01 = __shfl_xor(m01, m);
        float o10 = __shfl_xor(m10, m);
        float o11 = __shfl_xor(m11, m);
        float oL  = __shfl_xor(L, m);
        float og  = __shfl_xor(gold, m);
        bool up = (lane & m) != 0;
        float x00 = up ? o00 : m00, x01 = up ? o01 : m01;
        float x10 = up ? o10 : m10, x11 = up ? o11 : m11;
        float y00 = up ? m00 : o00, y01 = up ? m01 : o01;
        float y10 = up ? m10 : o10, y11 = up ? m11 : o11;
        m00 = fmaf(x00, y00, x01 * y10);
        m01 = fmaf(x00, y01, x01 * y11);
        m10 = fmaf(x10, y00, x11 * y10);
        m11 = fmaf(x10, y01, x11 * y11);
        L += oL;
        gold += og;
        float mx  = fmaxf(fmaxf(m00, m01), fmaxf(m10, m11));
        float inv = 1.0f / mx;
        L += __logf(mx);
        m00 *= inv; m01 *= inv; m10 *= inv; m11 *= inv;
    }

    if (lane == 0) {
        float tot = L + __logf(m00 + m01 + m10 + m11);
        out[b]      = gold;   // gold_score
        out[Bn + b] = tot;    // total_score
    }
}

extern "C" void kernel_launch(void* const* d_in, const int* in_sizes, int n_in,
                              void* d_out, int out_size, void* d_ws, size_t ws_size,
                              hipStream_t stream) {
    const float* emissions    = (const float*)d_in[0];
    const float* trans_params = (const float*)d_in[1];
    const int*   tags         = (const int*)d_in[2];
    const int*   who2who      = (const int*)d_in[3];
    const int*   intime       = (const int*)d_in[4];
    const int*   distance     = (const int*)d_in[5];
    float* out = (float*)d_out;

    float2* wsA = (float2*)d_ws;           // 8 MB
    float2* wsB = wsA + NM;                // 8 MB
    float2* wsC = wsB + NM;                // 8 MB   (24 MB total)

    crf_chunk<<<dim3(GRID), dim3(BLOCK), 0, stream>>>(
        emissions, trans_params, tags, who2who, intime, distance,
        wsA, wsB, wsC);
    crf_reduce<<<dim3(Bn / 4), dim3(BLOCK), 0, stream>>>(
        wsA, wsB, wsC, out);
}

// Round 7
// 199.682 us; speedup vs baseline: 1.0721x; 1.0721x over previous
//
#include <hip/hip_runtime.h>
#include <math.h>

// Problem constants (match reference setup_inputs)
#define Bn 4096
#define Sn 2048
#define BLOCK 1024               // 1 block = 1 sequence, 2 steps per thread

// =====================================================================
// Round 7: single fused kernel, FULLY COALESCED loads.
// R0-R6 all had lane-strided wave instructions (thread-contiguous CHUNK=8
// made lane i read base+i*64: 64 lines/instr, 16B used each, 4x re-touch).
// CHUNK=2 + BLOCK=1024 gives exactly one float4 (emissions) and one int2
// (each int array) per thread: every wave instruction is a dense
// contiguous 1KB/512B block. No transposes, no workspace round-trip.
// Math identical to the validated R2 linear-domain scan (absmax 8.0).
// =====================================================================
__global__ __launch_bounds__(BLOCK) void crf_fused(
    const float* __restrict__ emissions,     // [B, S, 2]
    const float* __restrict__ trans_params,  // [4, 2, 2]
    const int*   __restrict__ tags,          // [B, S]
    const int*   __restrict__ who2who,       // [B, S]
    const int*   __restrict__ intime,        // [B, S]
    const int*   __restrict__ distance,      // [B, S]
    float*       __restrict__ out)           // [2, B]
{
    const int b    = blockIdx.x;
    const int t    = threadIdx.x;            // owns steps 2t, 2t+1
    const int lane = t & 63;
    const int wave = t >> 6;                 // 16 waves
    const long base = (long)b * Sn;

    // sel banks: [sel][i][j] at [sel*4 + i*2 + j]; sel==0 is zero/ones
    __shared__ __align__(16) float lbank[20];   // log-domain (gold path)
    __shared__ __align__(16) float ebank[20];   // exp(trans)  (scan)
    __shared__ float sred[16][8];               // per-wave partials (padded)

    // ---- perfectly coalesced loads: lane-contiguous per instruction ----
    float4 e  = ((const float4*)(emissions + base * 2))[t]; // steps 2t,2t+1
    int2   tg = ((const int2*)(tags     + base))[t];
    int2   wh = ((const int2*)(who2who  + base))[t];
    int2   it = ((const int2*)(intime   + base))[t];
    int2   ds = ((const int2*)(distance + base))[t];
    // cross-wave prev tag: only lane 0 of waves 1..15 (1.5% of threads)
    int ptag = 0;
    if (lane == 0 && t > 0) ptag = tags[base + 2 * t - 1];

    if (t < 20) {
        float v = (t < 4) ? 0.0f : trans_params[t - 4];
        lbank[t] = v;
        ebank[t] = __expf(v);    // sel 0 -> all-ones matrix
    }
    __syncthreads();

    // ---- per-thread: compose 2 step matrices (linear domain) ----
    int sel0 = (wh.x == -1) ? 0 : (wh.x == 1) ? 1
             : (it.x == 0) ? 2 : (ds.x == 0) ? 3 : 4;
    int sel1 = (wh.y == -1) ? 0 : (wh.y == 1) ? 1
             : (it.y == 0) ? 2 : (ds.y == 0) ? 3 : 4;
    float4 P0 = *(const float4*)(ebank + sel0 * 4);
    float4 P1 = *(const float4*)(ebank + sel1 * 4);
    float x00 = __expf(e.x), x01 = __expf(e.y);   // step 2t emissions
    float x10 = __expf(e.z), x11 = __expf(e.w);   // step 2t+1

    float a00 = P0.x * x00, a01 = P0.y * x01;     // step matrices
    float a10 = P0.z * x00, a11 = P0.w * x01;
    float b00 = P1.x * x10, b01 = P1.y * x11;
    float b10 = P1.z * x10, b11 = P1.w * x11;
    float m00 = fmaf(a00, b00, a01 * b10);        // M = A (then) B
    float m01 = fmaf(a00, b01, a01 * b11);
    float m10 = fmaf(a10, b00, a11 * b10);
    float m11 = fmaf(a10, b01, a11 * b11);

    // gold path (log domain)
    float gold = (tg.x ? e.y : e.x) + (tg.y ? e.w : e.z);
    int pt0 = __shfl_up(tg.y, 1);                 // prev thread's last tag
    if (lane == 0) pt0 = ptag;
    if (t > 0)                                    // no transition at s==0
        gold += lbank[(sel0 << 2) + (pt0 << 1) + tg.x];
    gold += lbank[(sel1 << 2) + (tg.x << 1) + tg.y];

    // normalize; carry scale in log space
    float mx  = fmaxf(fmaxf(m00, m01), fmaxf(m10, m11));
    float inv = 1.0f / mx;
    float L   = __logf(mx);
    m00 *= inv; m01 *= inv; m10 *= inv; m11 *= inv;

    // ---- order-preserving in-wave butterfly (6 rounds, no renorm:
    //      normalized inputs -> growth <= 2^6, mixing prevents underflow;
    //      numerics validated R2-R6, absmax 8.0) ----
    #pragma unroll
    for (int m = 1; m < 64; m <<= 1) {
        float o00 = __shfl_xor(m00, m);
        float o01 = __shfl_xor(m01, m);
        float o10 = __shfl_xor(m10, m);
        float o11 = __shfl_xor(m11, m);
        float oL  = __shfl_xor(L, m);
        float og  = __shfl_xor(gold, m);
        bool up = (lane & m) != 0;
        float p00 = up ? o00 : m00, p01 = up ? o01 : m01;
        float p10 = up ? o10 : m10, p11 = up ? o11 : m11;
        float q00 = up ? m00 : o00, q01 = up ? m01 : o01;
        float q10 = up ? m10 : o10, q11 = up ? m11 : o11;
        m00 = fmaf(p00, q00, p01 * q10);
        m01 = fmaf(p00, q01, p01 * q11);
        m10 = fmaf(p10, q00, p11 * q10);
        m11 = fmaf(p10, q01, p11 * q11);
        L += oL;
        gold += og;
    }

    // ---- wave leaders publish renormalized partials ----
    if (lane == 0) {
        float mx2  = fmaxf(fmaxf(m00, m01), fmaxf(m10, m11));
        float inv2 = 1.0f / mx2;
        sred[wave][0] = m00 * inv2;
        sred[wave][1] = m01 * inv2;
        sred[wave][2] = m10 * inv2;
        sred[wave][3] = m11 * inv2;
        sred[wave][4] = L + __logf(mx2);
        sred[wave][5] = gold;
    }
    __syncthreads();

    // ---- wave 0, lanes 0..15: combine the 16 wave results in order ----
    if (wave == 0 && lane < 16) {
        float r00 = sred[lane][0], r01 = sred[lane][1];
        float r10 = sred[lane][2], r11 = sred[lane][3];
        float rL  = sred[lane][4], rg  = sred[lane][5];
        #pragma unroll
        for (int m = 1; m < 16; m <<= 1) {       // stays within lanes 0..15
            float o00 = __shfl_xor(r00, m);
            float o01 = __shfl_xor(r01, m);
            float o10 = __shfl_xor(r10, m);
            float o11 = __shfl_xor(r11, m);
            float oL  = __shfl_xor(rL, m);
            float og  = __shfl_xor(rg, m);
            bool up = (lane & m) != 0;
            float p00 = up ? o00 : r00, p01 = up ? o01 : r01;
            float p10 = up ? o10 : r10, p11 = up ? o11 : r11;
            float q00 = up ? r00 : o00, q01 = up ? r01 : o01;
            float q10 = up ? r10 : o10, q11 = up ? r11 : o11;
            r00 = fmaf(p00, q00, p01 * q10);
            r01 = fmaf(p00, q01, p01 * q11);
            r10 = fmaf(p10, q00, p11 * q10);
            r11 = fmaf(p10, q01, p11 * q11);
            rL += oL;
            rg += og;
        }
        if (lane == 0) {
            // total = L + log(sum of entries)   (alpha0 = zeros)
            float tot = rL + __logf(r00 + r01 + r10 + r11);
            out[b]      = rg;    // gold_score
            out[Bn + b] = tot;   // total_score
        }
    }
}

extern "C" void kernel_launch(void* const* d_in, const int* in_sizes, int n_in,
                              void* d_out, int out_size, void* d_ws, size_t ws_size,
                              hipStream_t stream) {
    const float* emissions    = (const float*)d_in[0];
    const float* trans_params = (const float*)d_in[1];
    const int*   tags         = (const int*)d_in[2];
    const int*   who2who      = (const int*)d_in[3];
    const int*   intime       = (const int*)d_in[4];
    const int*   distance     = (const int*)d_in[5];
    float* out = (float*)d_out;

    crf_fused<<<dim3(Bn), dim3(BLOCK), 0, stream>>>(
        emissions, trans_params, tags, who2who, intime, distance, out);
}